// Round 1
// baseline (66.995 us; speedup 1.0000x reference)
//
#include <hip/hip_runtime.h>

// LocalAveragePoolingSegmenter — prefix-sum approach.
// B=16, T_AUDIO=4096, T_TEXT=1024, D=512.
// Output = concat( segmented_feats [B,Tt,D] f32 , text_token_len [B] as f32 ).

constexpr int Bv = 16;
constexpr int TA = 4096;
constexpr int TT = 1024;
constexpr int Dv = 512;
constexpr int D4 = Dv / 4;   // 128 float4 per row
constexpr int CH = 64;       // chunk length (frames)
constexpr int NC = TA / CH;  // 64 chunks

// K1: local inclusive prefix within each 64-frame chunk, plus chunk totals.
// One thread per (b, chunk, d4). Consecutive threads -> consecutive d4 -> coalesced.
__global__ __launch_bounds__(256) void k_local_prefix(
    const float4* __restrict__ A, float4* __restrict__ L, float4* __restrict__ S)
{
    int g  = blockIdx.x * 256 + threadIdx.x;   // [0, Bv*NC*D4)
    int d4 = g & (D4 - 1);
    int c  = (g >> 7) & (NC - 1);
    int b  = g >> 13;
    size_t base = (size_t)(b * TA + c * CH) * D4 + d4;
    float4 acc = {0.f, 0.f, 0.f, 0.f};
    #pragma unroll 8
    for (int i = 0; i < CH; ++i) {
        float4 v = A[base + (size_t)i * D4];
        acc.x += v.x; acc.y += v.y; acc.z += v.z; acc.w += v.w;
        L[base + (size_t)i * D4] = acc;
    }
    S[(size_t)(b * NC + c) * D4 + d4] = acc;
}

// K2: exclusive scan of chunk totals along chunks, per (b, d) scalar lane.
__global__ __launch_bounds__(256) void k_chunk_scan(
    const float* __restrict__ S, float* __restrict__ C)
{
    int g = blockIdx.x * 256 + threadIdx.x;    // [0, Bv*Dv)
    int d = g & (Dv - 1);
    int b = g >> 9;
    float acc = 0.f;
    #pragma unroll 8
    for (int c = 0; c < NC; ++c) {
        size_t idx = (size_t)(b * NC + c) * Dv + d;
        C[idx] = acc;
        acc += S[idx];
    }
}

// K3: per-token segment mean via prefix difference.
// E[a] = sum of frames < a.  token sum = E[e+1] - E[s]
//   E[e+1] = C[e>>6] + L[e];   E[s] = (s==0) ? 0 : C[(s-1)>>6] + L[s-1]
__global__ __launch_bounds__(128) void k_segment(
    const float4* __restrict__ L, const float4* __restrict__ C,
    const int* __restrict__ tlen, const int* __restrict__ align,
    float4* __restrict__ out)
{
    int bt = blockIdx.x;            // b*TT + t
    int b  = bt >> 10;
    int t  = bt & (TT - 1);
    int d4 = threadIdx.x;           // 0..127
    size_t obase = (size_t)bt * D4 + d4;

    int len = tlen[b];
    if (t >= len) {
        out[obase] = make_float4(0.f, 0.f, 0.f, 0.f);
        return;
    }
    int s = align[2 * bt];
    int e = align[2 * bt + 1];      // sorted: 0 <= s <= e <= TA-1

    float4 hc = C[(size_t)(b * NC + (e >> 6)) * D4 + d4];
    float4 hl = L[(size_t)(b * TA + e) * D4 + d4];
    float sx = hc.x + hl.x;
    float sy = hc.y + hl.y;
    float sz = hc.z + hl.z;
    float sw = hc.w + hl.w;
    if (s > 0) {
        int j = s - 1;
        float4 lc = C[(size_t)(b * NC + (j >> 6)) * D4 + d4];
        float4 ll = L[(size_t)(b * TA + j) * D4 + d4];
        sx -= lc.x + ll.x;
        sy -= lc.y + ll.y;
        sz -= lc.z + ll.z;
        sw -= lc.w + ll.w;
    }
    float cnt = (float)(e - s + 1);
    float4 r;
    r.x = sx / cnt;
    r.y = sy / cnt;
    r.z = sz / cnt;
    r.w = sw / cnt;
    out[obase] = r;
}

// K4: second tuple output — text_token_len written as float32 into the tail.
__global__ void k_tail(const int* __restrict__ tlen, float* __restrict__ outt)
{
    int i = threadIdx.x;
    if (i < Bv) outt[i] = (float)tlen[i];
}

extern "C" void kernel_launch(void* const* d_in, const int* in_sizes, int n_in,
                              void* d_out, int out_size, void* d_ws, size_t ws_size,
                              hipStream_t stream)
{
    const float* audio = (const float*)d_in[0];        // [B,TA,D] f32
    const int*   tlen  = (const int*)d_in[4];          // [B] i32
    const int*   align = (const int*)d_in[5];          // [B,TT,2] i32
    float* out = (float*)d_out;

    // workspace layout: L [B*TA*D] f32, S [B*NC*D] f32, C [B*NC*D] f32
    float* L = (float*)d_ws;
    float* S = L + (size_t)Bv * TA * Dv;
    float* C = S + (size_t)Bv * NC * Dv;

    k_local_prefix<<<(Bv * NC * D4) / 256, 256, 0, stream>>>(
        (const float4*)audio, (float4*)L, (float4*)S);
    k_chunk_scan<<<(Bv * Dv) / 256, 256, 0, stream>>>(S, C);
    k_segment<<<Bv * TT, 128, 0, stream>>>(
        (const float4*)L, (const float4*)C, tlen, align, (float4*)out);
    k_tail<<<1, 64, 0, stream>>>(tlen, out + (size_t)Bv * TT * Dv);
}

// Round 2
// 57.547 us; speedup vs baseline: 1.1642x; 1.1642x over previous
//
#include <hip/hip_runtime.h>

// LocalAveragePoolingSegmenter — gran-4 hierarchical prefix, no frame-level L.
// B=16, T_AUDIO=4096, T_TEXT=1024, D=512.
// Output = concat( segmented_feats [B,Tt,D] f32 , text_token_len [B] as f32 ).

constexpr int Bv  = 16;
constexpr int TA  = 4096;
constexpr int TT  = 1024;
constexpr int Dv  = 512;
constexpr int D4  = Dv / 4;     // 128 float4 per row
constexpr int CH  = 16;         // frames per chunk
constexpr int NCk = TA / CH;    // 256 chunks per b
constexpr int NQ  = TA / 4;     // 1024 gran-4 prefix entries per b
constexpr int NQ1 = NQ + 1;     // +1 row for E[TA]

__device__ __forceinline__ void f4add(float4& a, const float4& v) {
    a.x += v.x; a.y += v.y; a.z += v.z; a.w += v.w;
}

// B1: per-chunk sums S + gran-4 LOCAL partial sums written into F slots (q%4 != 0).
// Thread per (b, chunk, d4); consecutive threads -> consecutive d4 (coalesced).
__global__ __launch_bounds__(256) void k_chunk_sums(
    const float4* __restrict__ A, float4* __restrict__ S, float4* __restrict__ F)
{
    int g  = blockIdx.x * 256 + threadIdx.x;   // [0, Bv*NCk*D4)
    int d4 = g & (D4 - 1);
    int c  = (g >> 7) & (NCk - 1);
    int b  = g >> 15;
    size_t abase = (size_t)(b * TA + c * CH) * D4 + d4;
    size_t fbase = ((size_t)b * NQ1 + 4 * c) * D4 + d4;
    float4 acc = {0.f, 0.f, 0.f, 0.f};
    #pragma unroll
    for (int i = 0; i < CH; ++i) {
        float4 v = A[abase + (size_t)i * D4];
        f4add(acc, v);
        if (i == 3)  F[fbase + 1 * D4] = acc;   // sum of frames [16c, 16c+4)
        if (i == 7)  F[fbase + 2 * D4] = acc;   // [16c, 16c+8)
        if (i == 11) F[fbase + 3 * D4] = acc;   // [16c, 16c+12)
    }
    S[(size_t)(b * NCk + c) * D4 + d4] = acc;
}

// B2: scan 256 chunk sums per (b,d4) column and fix F up in place.
// Block = 256 threads = 16 groups (g) x 16 columns (j); 16 chunks per (g,j) thread.
__global__ __launch_bounds__(256) void k_scan_fixup(
    const float4* __restrict__ S, float4* __restrict__ F)
{
    __shared__ float4 lds[16][16];
    int tid = threadIdx.x;
    int j  = tid & 15;
    int g  = tid >> 4;
    int b  = blockIdx.x >> 3;            // 8 blocks per b (128 d4 / 16)
    int d4 = (blockIdx.x & 7) * 16 + j;

    float4 sv[16];
    #pragma unroll
    for (int i = 0; i < 16; ++i)
        sv[i] = S[(size_t)(b * NCk + g * 16 + i) * D4 + d4];

    float4 run = {0.f, 0.f, 0.f, 0.f};
    float4 excl[16];
    #pragma unroll
    for (int i = 0; i < 16; ++i) {
        excl[i] = run;
        f4add(run, sv[i]);
    }
    lds[g][j] = run;                      // group totals
    __syncthreads();
    float4 go = {0.f, 0.f, 0.f, 0.f};     // exclusive offset across groups
    for (int gp = 0; gp < g; ++gp)
        f4add(go, lds[gp][j]);

    size_t fb = (size_t)b * NQ1 * D4 + d4;
    #pragma unroll
    for (int i = 0; i < 16; ++i) {
        int c = g * 16 + i;
        float4 cex = go;
        f4add(cex, excl[i]);              // E[16c] = global exclusive prefix of chunk c
        size_t q0 = (size_t)(4 * c) * D4;
        F[fb + q0] = cex;
        #pragma unroll
        for (int k = 1; k < 4; ++k) {     // F[4c+k] += cex (local partial written by B1)
            float4 v = F[fb + q0 + (size_t)k * D4];
            f4add(v, cex);
            F[fb + q0 + (size_t)k * D4] = v;
        }
    }
    if (g == 15) {                        // E[TA] = grand total
        float4 tot = go;
        f4add(tot, run);
        F[fb + (size_t)NQ * D4] = tot;
    }
}

// B4: per-token mean via gran-4 prefix difference + <=3 edge rows per boundary.
__global__ __launch_bounds__(128) void k_tokens(
    const float4* __restrict__ A, const float4* __restrict__ F,
    const int* __restrict__ tlen, const int* __restrict__ align,
    float4* __restrict__ out)
{
    int bt = blockIdx.x;                 // b*TT + t
    int b  = bt >> 10;
    int t  = bt & (TT - 1);
    int d4 = threadIdx.x;
    size_t obase = (size_t)bt * D4 + d4;

    if (t >= tlen[b]) {
        out[obase] = make_float4(0.f, 0.f, 0.f, 0.f);
        return;
    }
    int s = align[2 * bt];
    int e = align[2 * bt + 1];           // 0 <= s <= e <= TA-1
    int x0 = s, x1 = e + 1;
    int q0 = x0 >> 2, q1 = x1 >> 2;      // q1 <= NQ

    const float4* Fb = F + (size_t)b * NQ1 * D4;
    const float4* Ab = A + (size_t)b * TA * D4;

    float4 hi = Fb[(size_t)q1 * D4 + d4];            // E[4*q1]
    for (int f = 4 * q1; f < x1; ++f)                // 0..3 uniform iters
        f4add(hi, Ab[(size_t)f * D4 + d4]);
    float4 lo = Fb[(size_t)q0 * D4 + d4];            // E[4*q0]
    for (int f = 4 * q0; f < x0; ++f)                // 0..3 uniform iters
        f4add(lo, Ab[(size_t)f * D4 + d4]);

    float inv = 1.f / (float)(e - s + 1);
    float4 r;
    r.x = (hi.x - lo.x) * inv;
    r.y = (hi.y - lo.y) * inv;
    r.z = (hi.z - lo.z) * inv;
    r.w = (hi.w - lo.w) * inv;
    out[obase] = r;
}

// Tail: second tuple output — text_token_len as float32.
__global__ void k_tail(const int* __restrict__ tlen, float* __restrict__ outt)
{
    int i = threadIdx.x;
    if (i < Bv) outt[i] = (float)tlen[i];
}

extern "C" void kernel_launch(void* const* d_in, const int* in_sizes, int n_in,
                              void* d_out, int out_size, void* d_ws, size_t ws_size,
                              hipStream_t stream)
{
    const float* audio = (const float*)d_in[0];        // [B,TA,D] f32
    const int*   tlen  = (const int*)d_in[4];          // [B] i32
    const int*   align = (const int*)d_in[5];          // [B,TT,2] i32
    float* out = (float*)d_out;

    // ws layout (float4 units): S [Bv*NCk*D4], F [Bv*NQ1*D4]
    float4* S = (float4*)d_ws;
    float4* F = S + (size_t)Bv * NCk * D4;

    k_chunk_sums<<<(Bv * NCk * D4) / 256, 256, 0, stream>>>(
        (const float4*)audio, S, F);
    k_scan_fixup<<<(Bv * D4) / 16, 256, 0, stream>>>(S, F);
    k_tokens<<<Bv * TT, 128, 0, stream>>>(
        (const float4*)audio, F, tlen, align, (float4*)out);
    k_tail<<<1, 64, 0, stream>>>(tlen, out + (size_t)Bv * TT * Dv);
}

// Round 3
// 50.141 us; speedup vs baseline: 1.3361x; 1.1477x over previous
//
#include <hip/hip_runtime.h>

// LocalAveragePoolingSegmenter — gran-4 local partials + chunk-level scan.
// B=16, T_AUDIO=4096, T_TEXT=1024, D=512.
// Output = concat( segmented_feats [B,Tt,D] f32 , text_token_len [B] as f32 ).
//
// P[b][c][k][d4] (k=0..3): inclusive local sum of frames [16c, 16c+4(k+1)) — slot 3 = chunk sum.
// C[b][c][d4]   (c=0..256): global exclusive prefix at chunk granularity (C[256] = total).
// E[x] = C[x>>4] + (k? P[..][k-1] : 0) + up to 3 audio edge rows,  k=(x>>2)&3.

constexpr int Bv  = 16;
constexpr int TA  = 4096;
constexpr int TT  = 1024;
constexpr int Dv  = 512;
constexpr int D4  = Dv / 4;     // 128 float4 per row
constexpr int CH  = 16;         // frames per chunk
constexpr int NCk = TA / CH;    // 256 chunks per b
constexpr int NC1 = NCk + 1;

typedef float f32x4 __attribute__((ext_vector_type(4)));

__device__ __forceinline__ void f4add(float4& a, const float4& v) {
    a.x += v.x; a.y += v.y; a.z += v.z; a.w += v.w;
}

// K1: per (b, chunk, d4): local inclusive partials at 4/8/12/16 frames -> P slots 0..3.
__global__ __launch_bounds__(256) void k_partials(
    const float4* __restrict__ A, float4* __restrict__ P)
{
    int g  = blockIdx.x * 256 + threadIdx.x;   // [0, Bv*NCk*D4)
    int d4 = g & (D4 - 1);
    int c  = (g >> 7) & (NCk - 1);
    int b  = g >> 15;
    size_t abase = (size_t)(b * TA + c * CH) * D4 + d4;
    size_t pbase = ((size_t)(b * NCk + c) * 4) * D4 + d4;
    float4 acc = {0.f, 0.f, 0.f, 0.f};
    #pragma unroll
    for (int i = 0; i < CH; ++i) {
        float4 v = A[abase + (size_t)i * D4];
        f4add(acc, v);
        if (i == 3)  P[pbase]           = acc;
        if (i == 7)  P[pbase +     D4]  = acc;
        if (i == 11) P[pbase + 2 * D4]  = acc;
        if (i == 15) P[pbase + 3 * D4]  = acc;
    }
}

// K2: chunk-level exclusive scan (P slot 3 -> C), + tail lens output fused in.
// Block = 256 threads = 16 groups (g) x 16 cols (j); 8 blocks per b.
__global__ __launch_bounds__(256) void k_scan(
    const float4* __restrict__ P, float4* __restrict__ C,
    const int* __restrict__ tlen, float* __restrict__ outt)
{
    __shared__ float4 lds[16][16];
    int tid = threadIdx.x;
    int j  = tid & 15;
    int g  = tid >> 4;
    int b  = blockIdx.x >> 3;
    int d4 = (blockIdx.x & 7) * 16 + j;

    float4 run = {0.f, 0.f, 0.f, 0.f};
    float4 excl[16];
    #pragma unroll
    for (int i = 0; i < 16; ++i) {
        excl[i] = run;
        float4 s = P[((size_t)(b * NCk + g * 16 + i) * 4 + 3) * D4 + d4];
        f4add(run, s);
    }
    lds[g][j] = run;                       // group total
    __syncthreads();
    float4 go = {0.f, 0.f, 0.f, 0.f};      // exclusive offset over groups
    for (int gp = 0; gp < g; ++gp)
        f4add(go, lds[gp][j]);

    size_t cb = (size_t)b * NC1 * D4 + d4;
    #pragma unroll
    for (int i = 0; i < 16; ++i) {
        float4 cex = go;
        f4add(cex, excl[i]);
        C[cb + (size_t)(g * 16 + i) * D4] = cex;
    }
    if (g == 15) {
        float4 tot = go;
        f4add(tot, run);
        C[cb + (size_t)NCk * D4] = tot;    // C[b][256] = grand total
    }
    if (blockIdx.x == 0 && tid < Bv)
        outt[tid] = (float)tlen[tid];
}

// K3: per-token mean via C + P + <=3 edge rows per boundary. Non-temporal out.
__global__ __launch_bounds__(128) void k_tokens(
    const float4* __restrict__ A, const float4* __restrict__ P,
    const float4* __restrict__ C, const int* __restrict__ tlen,
    const int* __restrict__ align, float4* __restrict__ out)
{
    int bt = blockIdx.x;                 // b*TT + t
    int b  = bt >> 10;
    int t  = bt & (TT - 1);
    int d4 = threadIdx.x;
    size_t ob = (size_t)bt * D4 + d4;

    if (t >= tlen[b]) {
        f32x4 z = {0.f, 0.f, 0.f, 0.f};
        __builtin_nontemporal_store(z, (f32x4*)&out[ob]);
        return;
    }
    int s = align[2 * bt];
    int e = align[2 * bt + 1];           // 0 <= s <= e <= TA-1

    const float4* Ab = A + (size_t)b * TA * D4;
    const float4* Cb = C + (size_t)b * NC1 * D4;
    const float4* Pb = P + (size_t)b * NCk * 4 * D4;

    auto Eval = [&](int x) -> float4 {   // sum of frames < x, x in [0, TA]
        int c = x >> 4;
        int k = (x >> 2) & 3;
        float4 v = Cb[(size_t)c * D4 + d4];
        if (k) f4add(v, Pb[((size_t)c * 4 + (k - 1)) * D4 + d4]);
        for (int f = (x & ~3); f < x; ++f)       // 0..3 uniform iters
            f4add(v, Ab[(size_t)f * D4 + d4]);
        return v;
    };

    float4 hi = Eval(e + 1);
    float4 lo = Eval(s);
    float inv = 1.f / (float)(e - s + 1);
    f32x4 r = { (hi.x - lo.x) * inv, (hi.y - lo.y) * inv,
                (hi.z - lo.z) * inv, (hi.w - lo.w) * inv };
    __builtin_nontemporal_store(r, (f32x4*)&out[ob]);
}

extern "C" void kernel_launch(void* const* d_in, const int* in_sizes, int n_in,
                              void* d_out, int out_size, void* d_ws, size_t ws_size,
                              hipStream_t stream)
{
    const float* audio = (const float*)d_in[0];        // [B,TA,D] f32
    const int*   tlen  = (const int*)d_in[4];          // [B] i32
    const int*   align = (const int*)d_in[5];          // [B,TT,2] i32
    float* out = (float*)d_out;

    // ws layout (float4 units): P [Bv*NCk*4*D4], C [Bv*NC1*D4]
    float4* P = (float4*)d_ws;
    float4* C = P + (size_t)Bv * NCk * 4 * D4;

    k_partials<<<(Bv * NCk * D4) / 256, 256, 0, stream>>>(
        (const float4*)audio, P);
    k_scan<<<(Bv * D4) / 16, 256, 0, stream>>>(
        P, C, tlen, out + (size_t)Bv * TT * Dv);
    k_tokens<<<Bv * TT, 128, 0, stream>>>(
        (const float4*)audio, P, C, tlen, align, (float4*)out);
}

// Round 4
// 49.119 us; speedup vs baseline: 1.3639x; 1.0208x over previous
//
#include <hip/hip_runtime.h>

// LocalAveragePoolingSegmenter — gran-4 local partials + chunk scan + XCD-affine token kernel.
// B=16, T_AUDIO=4096, T_TEXT=1024, D=512.
// Output = concat( segmented_feats [B,Tt,D] f32 , text_token_len [B] as f32 ).
//
// P3[b][c][k][d4] (k=0..2): local inclusive sum of frames [16c, 16c+4(k+1)).
// S [b][c][d4]            : chunk sums (16 frames).
// C [b][c][d4] (c=0..256) : global exclusive prefix at chunk granularity (C[256]=total).
// E[x] = C[x>>4] + (k? P3[..][k-1] : 0) + up to 3 audio edge rows, k=(x>>2)&3.

constexpr int Bv  = 16;
constexpr int TA  = 4096;
constexpr int TT  = 1024;
constexpr int Dv  = 512;
constexpr int D4  = Dv / 4;     // 128 float4 per row
constexpr int CH  = 16;         // frames per chunk
constexpr int NCk = TA / CH;    // 256 chunks per b
constexpr int NC1 = NCk + 1;

typedef float f32x4 __attribute__((ext_vector_type(4)));

__device__ __forceinline__ void f4add(float4& a, const float4& v) {
    a.x += v.x; a.y += v.y; a.z += v.z; a.w += v.w;
}

// K1: per (b, chunk, d4): local partials at 4/8/12 frames -> P3, chunk total -> S.
__global__ __launch_bounds__(256) void k_partials(
    const float4* __restrict__ A, float4* __restrict__ P3, float4* __restrict__ S)
{
    int g  = blockIdx.x * 256 + threadIdx.x;   // [0, Bv*NCk*D4)
    int d4 = g & (D4 - 1);
    int c  = (g >> 7) & (NCk - 1);
    int b  = g >> 15;
    size_t abase = (size_t)(b * TA + c * CH) * D4 + d4;
    size_t pbase = ((size_t)(b * NCk + c) * 3) * D4 + d4;
    float4 acc = {0.f, 0.f, 0.f, 0.f};
    #pragma unroll
    for (int i = 0; i < CH; ++i) {
        float4 v = A[abase + (size_t)i * D4];
        f4add(acc, v);
        if (i == 3)  P3[pbase]          = acc;
        if (i == 7)  P3[pbase +     D4] = acc;
        if (i == 11) P3[pbase + 2 * D4] = acc;
    }
    S[(size_t)(b * NCk + c) * D4 + d4] = acc;
}

// K2: chunk-level exclusive scan S -> C, + tail lens output fused in.
// Block = 256 threads = 16 groups (g) x 16 cols (j); 8 blocks per b.
__global__ __launch_bounds__(256) void k_scan(
    const float4* __restrict__ S, float4* __restrict__ C,
    const int* __restrict__ tlen, float* __restrict__ outt)
{
    __shared__ float4 lds[16][16];
    int tid = threadIdx.x;
    int j  = tid & 15;
    int g  = tid >> 4;
    int b  = blockIdx.x >> 3;
    int d4 = (blockIdx.x & 7) * 16 + j;

    float4 run = {0.f, 0.f, 0.f, 0.f};
    float4 excl[16];
    #pragma unroll
    for (int i = 0; i < 16; ++i) {
        excl[i] = run;
        float4 s = S[(size_t)(b * NCk + g * 16 + i) * D4 + d4];
        f4add(run, s);
    }
    lds[g][j] = run;                       // group total
    __syncthreads();
    float4 go = {0.f, 0.f, 0.f, 0.f};      // exclusive offset over groups
    for (int gp = 0; gp < g; ++gp)
        f4add(go, lds[gp][j]);

    size_t cb = (size_t)b * NC1 * D4 + d4;
    #pragma unroll
    for (int i = 0; i < 16; ++i) {
        float4 cex = go;
        f4add(cex, excl[i]);
        C[cb + (size_t)(g * 16 + i) * D4] = cex;
    }
    if (g == 15) {
        float4 tot = go;
        f4add(tot, run);
        C[cb + (size_t)NCk * D4] = tot;    // C[b][256] = grand total
    }
    if (blockIdx.x == 0 && tid < Bv)
        outt[tid] = (float)tlen[tid];
}

// K3: per-token mean. XCD-affine mapping: batch b pinned to XCD b&7, so each
// XCD's L2 (4 MiB) holds its two batches' C (0.5 MB) + P3 (1.57 MB) rows.
__global__ __launch_bounds__(128) void k_tokens(
    const float4* __restrict__ A, const float4* __restrict__ P3,
    const float4* __restrict__ C, const int* __restrict__ tlen,
    const int* __restrict__ align, float4* __restrict__ out)
{
    // blocks dispatch round-robin over 8 XCDs: block i -> XCD i&7.
    int xcd  = blockIdx.x & 7;
    int slot = blockIdx.x >> 3;            // [0, 2048)
    int b  = xcd + 8 * (slot >> 10);       // batches {xcd, xcd+8} on this XCD
    int t  = slot & (TT - 1);
    int bt = b * TT + t;
    int d4 = threadIdx.x;
    size_t ob = (size_t)bt * D4 + d4;

    if (t >= tlen[b]) {
        f32x4 z = {0.f, 0.f, 0.f, 0.f};
        __builtin_nontemporal_store(z, (f32x4*)&out[ob]);
        return;
    }
    int s = align[2 * bt];
    int e = align[2 * bt + 1];           // 0 <= s <= e <= TA-1

    const float4* Ab = A  + (size_t)b * TA * D4;
    const float4* Cb = C  + (size_t)b * NC1 * D4;
    const float4* Pb = P3 + (size_t)b * NCk * 3 * D4;

    auto Eval = [&](int x) -> float4 {   // sum of frames < x, x in [0, TA]
        int c = x >> 4;
        int k = (x >> 2) & 3;
        float4 v = Cb[(size_t)c * D4 + d4];
        if (k) f4add(v, Pb[((size_t)c * 3 + (k - 1)) * D4 + d4]);
        for (int f = (x & ~3); f < x; ++f)       // 0..3 uniform iters
            f4add(v, Ab[(size_t)f * D4 + d4]);
        return v;
    };

    float4 hi = Eval(e + 1);
    float4 lo = Eval(s);
    float inv = 1.f / (float)(e - s + 1);
    f32x4 r = { (hi.x - lo.x) * inv, (hi.y - lo.y) * inv,
                (hi.z - lo.z) * inv, (hi.w - lo.w) * inv };
    __builtin_nontemporal_store(r, (f32x4*)&out[ob]);
}

extern "C" void kernel_launch(void* const* d_in, const int* in_sizes, int n_in,
                              void* d_out, int out_size, void* d_ws, size_t ws_size,
                              hipStream_t stream)
{
    const float* audio = (const float*)d_in[0];        // [B,TA,D] f32
    const int*   tlen  = (const int*)d_in[4];          // [B] i32
    const int*   align = (const int*)d_in[5];          // [B,TT,2] i32
    float* out = (float*)d_out;

    // ws layout (float4 units): P3 [Bv*NCk*3*D4], S [Bv*NCk*D4], C [Bv*NC1*D4]
    float4* P3 = (float4*)d_ws;
    float4* S  = P3 + (size_t)Bv * NCk * 3 * D4;
    float4* C  = S  + (size_t)Bv * NCk * D4;

    k_partials<<<(Bv * NCk * D4) / 256, 256, 0, stream>>>(
        (const float4*)audio, P3, S);
    k_scan<<<(Bv * D4) / 16, 256, 0, stream>>>(
        S, C, tlen, out + (size_t)Bv * TT * Dv);
    k_tokens<<<Bv * TT, 128, 0, stream>>>(
        (const float4*)audio, P3, C, tlen, align, (float4*)out);
}

// Round 5
// 44.866 us; speedup vs baseline: 1.4932x; 1.0948x over previous
//
#include <hip/hip_runtime.h>

// LocalAveragePoolingSegmenter — gran-2 fp16 local partials + fp32 chunk scan
// + XCD-affine token kernel.
// B=16, T_AUDIO=4096, T_TEXT=1024, D=512.
// Output = concat( segmented_feats [B,Tt,D] f32 , text_token_len [B] as f32 ).
//
// P[b][c][j][d4] (j=0..6, fp16): local inclusive sum of frames [16c, 16c+2(j+1)).
// S [b][c][d4]   (fp32)        : chunk sums (16 frames).
// C [b][c][d4]   (c=0..256)    : global exclusive prefix at chunk granularity.
// E[x] = C[x>>4] + (k2? P[..][k2-1] : 0) + (x&1 ? audio[x-1] : 0),  k2=(x&15)>>1.

constexpr int Bv  = 16;
constexpr int TA  = 4096;
constexpr int TT  = 1024;
constexpr int Dv  = 512;
constexpr int D4  = Dv / 4;     // 128 float4 per row
constexpr int CH  = 16;         // frames per chunk
constexpr int NCk = TA / CH;    // 256 chunks per b
constexpr int NC1 = NCk + 1;
constexpr int NSL = 7;          // gran-2 partial slots per chunk

typedef float    f32x4 __attribute__((ext_vector_type(4)));
typedef _Float16 f16x4 __attribute__((ext_vector_type(4)));

__device__ __forceinline__ void f4add(float4& a, const float4& v) {
    a.x += v.x; a.y += v.y; a.z += v.z; a.w += v.w;
}
__device__ __forceinline__ void f4addh(float4& a, const f16x4& v) {
    a.x += (float)v.x; a.y += (float)v.y; a.z += (float)v.z; a.w += (float)v.w;
}
__device__ __forceinline__ f16x4 toh4(const float4& v) {
    f16x4 r = { (_Float16)v.x, (_Float16)v.y, (_Float16)v.z, (_Float16)v.w };
    return r;
}

// K1: per (b, chunk, d4): fp16 gran-2 partials (7 slots) -> P, fp32 chunk total -> S.
__global__ __launch_bounds__(256) void k_partials(
    const float4* __restrict__ A, f16x4* __restrict__ P, float4* __restrict__ S)
{
    int g  = blockIdx.x * 256 + threadIdx.x;   // [0, Bv*NCk*D4)
    int d4 = g & (D4 - 1);
    int c  = (g >> 7) & (NCk - 1);
    int b  = g >> 15;
    size_t abase = (size_t)(b * TA + c * CH) * D4 + d4;
    size_t pbase = ((size_t)(b * NCk + c) * NSL) * D4 + d4;
    float4 acc = {0.f, 0.f, 0.f, 0.f};
    #pragma unroll
    for (int i = 0; i < CH; ++i) {
        float4 v = A[abase + (size_t)i * D4];
        f4add(acc, v);
        if ((i & 1) && i < 15)                 // i = 1,3,...,13 -> slot (i-1)/2
            P[pbase + (size_t)((i - 1) >> 1) * D4] = toh4(acc);
    }
    S[(size_t)(b * NCk + c) * D4 + d4] = acc;
}

// K2: chunk-level exclusive scan S -> C (fp32), + tail lens output fused in.
// Block = 256 threads = 16 groups (g) x 16 cols (j); 8 blocks per b.
__global__ __launch_bounds__(256) void k_scan(
    const float4* __restrict__ S, float4* __restrict__ C,
    const int* __restrict__ tlen, float* __restrict__ outt)
{
    __shared__ float4 lds[16][16];
    int tid = threadIdx.x;
    int j  = tid & 15;
    int g  = tid >> 4;
    int b  = blockIdx.x >> 3;
    int d4 = (blockIdx.x & 7) * 16 + j;

    float4 run = {0.f, 0.f, 0.f, 0.f};
    float4 excl[16];
    #pragma unroll
    for (int i = 0; i < 16; ++i) {
        excl[i] = run;
        float4 s = S[(size_t)(b * NCk + g * 16 + i) * D4 + d4];
        f4add(run, s);
    }
    lds[g][j] = run;                       // group total
    __syncthreads();
    float4 go = {0.f, 0.f, 0.f, 0.f};      // exclusive offset over groups
    for (int gp = 0; gp < g; ++gp)
        f4add(go, lds[gp][j]);

    size_t cb = (size_t)b * NC1 * D4 + d4;
    #pragma unroll
    for (int i = 0; i < 16; ++i) {
        float4 cex = go;
        f4add(cex, excl[i]);
        C[cb + (size_t)(g * 16 + i) * D4] = cex;
    }
    if (g == 15) {
        float4 tot = go;
        f4add(tot, run);
        C[cb + (size_t)NCk * D4] = tot;    // C[b][256] = grand total
    }
    if (blockIdx.x == 0 && tid < Bv)
        outt[tid] = (float)tlen[tid];
}

// K3: per-token mean. XCD-affine: batch b pinned to XCD b&7 (C/P L2-resident).
__global__ __launch_bounds__(128) void k_tokens(
    const float4* __restrict__ A, const f16x4* __restrict__ P,
    const float4* __restrict__ C, const int* __restrict__ tlen,
    const int* __restrict__ align, float4* __restrict__ out)
{
    int xcd  = blockIdx.x & 7;
    int slot = blockIdx.x >> 3;            // [0, 2048)
    int b  = xcd + 8 * (slot >> 10);       // batches {xcd, xcd+8}
    int t  = slot & (TT - 1);
    int bt = b * TT + t;
    int d4 = threadIdx.x;
    size_t ob = (size_t)bt * D4 + d4;

    if (t >= tlen[b]) {
        f32x4 z = {0.f, 0.f, 0.f, 0.f};
        __builtin_nontemporal_store(z, (f32x4*)&out[ob]);
        return;
    }
    int s = align[2 * bt];
    int e = align[2 * bt + 1];           // 0 <= s <= e <= TA-1

    const float4* Ab = A + (size_t)b * TA * D4;
    const float4* Cb = C + (size_t)b * NC1 * D4;
    const f16x4*  Pb = P + (size_t)b * NCk * NSL * D4;

    auto Eval = [&](int x) -> float4 {   // sum of frames < x, x in [0, TA]
        int c  = x >> 4;
        int k2 = (x & 15) >> 1;
        float4 v = Cb[(size_t)c * D4 + d4];
        if (k2) f4addh(v, Pb[((size_t)c * NSL + (k2 - 1)) * D4 + d4]);
        if (x & 1) f4add(v, Ab[(size_t)(x - 1) * D4 + d4]);
        return v;
    };

    float4 hi = Eval(e + 1);
    float4 lo = Eval(s);
    float inv = 1.f / (float)(e - s + 1);
    f32x4 r = { (hi.x - lo.x) * inv, (hi.y - lo.y) * inv,
                (hi.z - lo.z) * inv, (hi.w - lo.w) * inv };
    __builtin_nontemporal_store(r, (f32x4*)&out[ob]);
}

extern "C" void kernel_launch(void* const* d_in, const int* in_sizes, int n_in,
                              void* d_out, int out_size, void* d_ws, size_t ws_size,
                              hipStream_t stream)
{
    const float* audio = (const float*)d_in[0];        // [B,TA,D] f32
    const int*   tlen  = (const int*)d_in[4];          // [B] i32
    const int*   align = (const int*)d_in[5];          // [B,TT,2] i32
    float* out = (float*)d_out;

    // ws layout: P fp16 [Bv*NCk*NSL*D4] (29.4 MB), then S, C fp32.
    f16x4*  P = (f16x4*)d_ws;
    float4* S = (float4*)((char*)d_ws + (size_t)Bv * NCk * NSL * D4 * sizeof(f16x4));
    float4* C = S + (size_t)Bv * NCk * D4;

    k_partials<<<(Bv * NCk * D4) / 256, 256, 0, stream>>>(
        (const float4*)audio, P, S);
    k_scan<<<(Bv * D4) / 16, 256, 0, stream>>>(
        S, C, tlen, out + (size_t)Bv * TT * Dv);
    k_tokens<<<Bv * TT, 128, 0, stream>>>(
        (const float4*)audio, P, C, tlen, align, (float4*)out);
}